// Round 1
// baseline (22953.070 us; speedup 1.0000x reference)
//
#include <hip/hip_runtime.h>

#define DIM 128
#define NB 4
#define NE 1024
#define TPB 64          // tokens per block
#define CCH 64          // codes per LDS chunk
#define NCH (NE / CCH)  // 16
#define NTOK 65536
#define THREADS 256

__device__ __forceinline__ int swz16(int d) { return 4 * ((d >> 2) & 15); }

// 0.5 * ||e||^2 for all 4*1024 codes -> d_ws
__global__ __launch_bounds__(64) void rvq_norms(const float* __restrict__ books,
                                                float* __restrict__ hn) {
    int code = blockIdx.x;  // 0 .. NB*NE-1
    const float* e = books + (size_t)code * DIM;
    int l = threadIdx.x;
    float a = e[l], b = e[l + 64];
    float s = a * a + b * b;
#pragma unroll
    for (int off = 32; off; off >>= 1) s += __shfl_xor(s, off);
    if (l == 0) hn[code] = 0.5f * s;
}

__global__ __launch_bounds__(THREADS) void rvq_main(const float* __restrict__ z,
                                                    const float* __restrict__ books,
                                                    const float* __restrict__ hnorm,
                                                    float* __restrict__ out) {
    __shared__ float resid[DIM][TPB];       // 32 KB, swizzled cols
    __shared__ float cbuf[2][DIM][CCH];     // 64 KB, transposed [dim][code], swizzled
    __shared__ int bidx[TPB];

    const int tid = threadIdx.x;
    const int r = tid >> 4;   // token group 0..15 (4 tokens each)
    const int c = tid & 15;   // code group  0..15 (4 codes each)
    const size_t tok0 = (size_t)blockIdx.x * TPB;
    const int bb = (int)(tok0 >> 11);       // batch (2048 tokens per batch, 64 | 2048)
    const int tin = (int)(tok0 & 2047);
    const size_t zbase = (size_t)bb * DIM * 2048 + tin;

    // stage residual: resid[d][t] = z[b][d][t]
    for (int i = tid; i < DIM * TPB; i += THREADS) {
        int d = i >> 6, t = i & 63;                     // lanes: t consecutive -> coalesced
        resid[d][t ^ swz16(d)] = z[zbase + (size_t)d * 2048 + t];
    }

    const char* rbase = (const char*)&resid[0][0];
    const int aoff = 16 * r;  // byte offset for this thread's 4 tokens
    const int boff = 16 * c;  // byte offset for this thread's 4 codes

    for (int book = 0; book < NB; ++book) {
        const float* bk = books + (size_t)book * NE * DIM;

        // stage chunk 0 -> buf 0  (transpose: [code][dim] -> [dim][code])
        {
            float4 pre[8];
#pragma unroll
            for (int j = 0; j < 8; ++j) {
                int f = tid + 256 * j;
                int cc = f >> 5, d4 = f & 31;           // lanes: d4 consecutive -> coalesced
                pre[j] = *(const float4*)(bk + (size_t)cc * DIM + 4 * d4);
            }
#pragma unroll
            for (int j = 0; j < 8; ++j) {
                int f = tid + 256 * j;
                int cc = f >> 5, d4 = f & 31;
                int col = cc ^ (4 * (d4 & 15));
                cbuf[0][4 * d4 + 0][col] = pre[j].x;
                cbuf[0][4 * d4 + 1][col] = pre[j].y;
                cbuf[0][4 * d4 + 2][col] = pre[j].z;
                cbuf[0][4 * d4 + 3][col] = pre[j].w;
            }
        }
        float bval[4] = {-1e30f, -1e30f, -1e30f, -1e30f};
        int bcode[4] = {0, 0, 0, 0};
        __syncthreads();

        for (int ch = 0; ch < NCH; ++ch) {
            const int rb = ch & 1;
            float4 pre[8];
            const bool hasNext = (ch + 1 < NCH);
            if (hasNext) {  // issue next-chunk global loads early (hide under FMA)
                const float* src = bk + (size_t)(ch + 1) * CCH * DIM;
#pragma unroll
                for (int j = 0; j < 8; ++j) {
                    int f = tid + 256 * j;
                    int cc = f >> 5, d4 = f & 31;
                    pre[j] = *(const float4*)(src + (size_t)cc * DIM + 4 * d4);
                }
            }
            const char* cb = (const char*)&cbuf[rb][0][0];
            float acc[4][4] = {};
#pragma unroll
            for (int k = 0; k < DIM; ++k) {
                const int sw = 16 * ((k >> 2) & 15);
                float4 a = *(const float4*)(rbase + k * (TPB * 4) + (aoff ^ sw));
                float4 b = *(const float4*)(cb + k * (CCH * 4) + (boff ^ sw));
                acc[0][0] += a.x * b.x; acc[0][1] += a.x * b.y; acc[0][2] += a.x * b.z; acc[0][3] += a.x * b.w;
                acc[1][0] += a.y * b.x; acc[1][1] += a.y * b.y; acc[1][2] += a.y * b.z; acc[1][3] += a.y * b.w;
                acc[2][0] += a.z * b.x; acc[2][1] += a.z * b.y; acc[2][2] += a.z * b.z; acc[2][3] += a.z * b.w;
                acc[3][0] += a.w * b.x; acc[3][1] += a.w * b.y; acc[3][2] += a.w * b.z; acc[3][3] += a.w * b.w;
            }
            const float* hn = hnorm + book * NE + ch * CCH + 4 * c;
#pragma unroll
            for (int i = 0; i < 4; ++i) {
                float h = hn[i];
                int code = ch * CCH + 4 * c + i;       // ascending scan -> strict '>' keeps first max
#pragma unroll
                for (int j = 0; j < 4; ++j) {
                    float s = acc[j][i] - h;
                    if (s > bval[j]) { bval[j] = s; bcode[j] = code; }
                }
            }
            if (hasNext) {
                const int wb = rb ^ 1;
#pragma unroll
                for (int j = 0; j < 8; ++j) {
                    int f = tid + 256 * j;
                    int cc = f >> 5, d4 = f & 31;
                    int col = cc ^ (4 * (d4 & 15));
                    cbuf[wb][4 * d4 + 0][col] = pre[j].x;
                    cbuf[wb][4 * d4 + 1][col] = pre[j].y;
                    cbuf[wb][4 * d4 + 2][col] = pre[j].z;
                    cbuf[wb][4 * d4 + 3][col] = pre[j].w;
                }
            }
            __syncthreads();
        }

        // reduce (bval,bcode) across the 16 code-column threads (lanes xor 1,2,4,8)
#pragma unroll
        for (int j = 0; j < 4; ++j) {
            float v = bval[j];
            int ix = bcode[j];
#pragma unroll
            for (int off = 1; off < 16; off <<= 1) {
                float ov = __shfl_xor(v, off);
                int oi = __shfl_xor(ix, off);
                if (ov > v || (ov == v && oi < ix)) { v = ov; ix = oi; }
            }
            if (c == 0) bidx[4 * r + j] = ix;
        }
        __syncthreads();

        // residual -= gathered code  (global read coalesced along d)
        for (int i = tid; i < DIM * TPB; i += THREADS) {
            int d = i & 127, t = i >> 7;               // t wave-uniform; d consecutive
            float q = bk[(size_t)bidx[t] * DIM + d];
            resid[d][t ^ swz16(d)] -= q;
        }
        __syncthreads();
    }

    // out = x - residual_final  (== sum of selected codes)
    for (int i = tid; i < DIM * TPB; i += THREADS) {
        int d = i >> 6, t = i & 63;
        size_t off = zbase + (size_t)d * 2048 + t;
        out[off] = z[off] - resid[d][t ^ swz16(d)];
    }
}

extern "C" void kernel_launch(void* const* d_in, const int* in_sizes, int n_in,
                              void* d_out, int out_size, void* d_ws, size_t ws_size,
                              hipStream_t stream) {
    const float* z = (const float*)d_in[0];      // [32,128,2048] f32
    const float* books = (const float*)d_in[1];  // [4,1024,128]  f32
    float* out = (float*)d_out;                  // [32,128,2048] f32
    float* hn = (float*)d_ws;                    // 4096 floats scratch

    rvq_norms<<<NB * NE, 64, 0, stream>>>(books, hn);
    rvq_main<<<NTOK / TPB, THREADS, 0, stream>>>(z, books, hn, out);
}

// Round 2
// 1086.050 us; speedup vs baseline: 21.1345x; 21.1345x over previous
//
#include <hip/hip_runtime.h>

#define DIM 128
#define NB 4
#define NE 1024
#define TPB 64          // tokens per block
#define CCH 64          // codes per LDS chunk
#define NCH (NE / CCH)  // 16
#define NTOK 65536
#define THREADS 256

__device__ __forceinline__ void gload_lds16(const void* g, void* l) {
    __builtin_amdgcn_global_load_lds(
        (const __attribute__((address_space(1))) void*)g,
        (__attribute__((address_space(3))) void*)l, 16, 0, 0);
}

// 0.5 * ||e||^2 for all 4*1024 codes -> d_ws
__global__ __launch_bounds__(64) void rvq_norms(const float* __restrict__ books,
                                                float* __restrict__ hn) {
    int code = blockIdx.x;
    const float* e = books + (size_t)code * DIM;
    int l = threadIdx.x;
    float a = e[l], b = e[l + 64];
    float s = a * a + b * b;
#pragma unroll
    for (int off = 32; off; off >>= 1) s += __shfl_xor(s, off);
    if (l == 0) hn[code] = 0.5f * s;
}

__global__ __launch_bounds__(THREADS, 2) void rvq_main(const float* __restrict__ z,
                                                       const float* __restrict__ books,
                                                       const float* __restrict__ hnorm,
                                                       float* __restrict__ out) {
    // row-major [row][dim], 16B granules XOR-swizzled by (row>>2)&7
    __shared__ float resid[TPB][DIM];   // 32 KB
    __shared__ float cbuf[CCH][DIM];    // 32 KB, single buffer, staged via global_load_lds
    __shared__ int bidx[TPB];

    const int tid = threadIdx.x;
    const int r = tid >> 4;     // token group 0..15 (4 tokens)
    const int c = tid & 15;     // code group  0..15 (4 codes)
    const int wv = tid >> 6;    // wave 0..3
    const int ln = tid & 63;

    const size_t tok0 = (size_t)blockIdx.x * TPB;
    const int bb = (int)(tok0 >> 11);
    const int tin = (int)(tok0 & 2047);
    const size_t zbase = (size_t)bb * (DIM * 2048) + tin;

    // stage residual: resid[t][d] = z[b][d][t] (transpose; one-time cost)
    for (int i = tid; i < TPB * DIM; i += THREADS) {
        int d = i >> 6, t = i & 63;  // lanes along t -> coalesced global read
        int g = d >> 2, e = d & 3;
        resid[t][(((g ^ ((t >> 2) & 7)) << 2) | e)] = z[zbase + (size_t)d * 2048 + t];
    }

    const int swA = r & 7;      // (token>>2)&7 == r&7 for tokens 4r..4r+3
    const int swB = c & 7;      // (code>>2)&7  == c&7 for codes  4c..4c+3
    const int tr = 4 * r, tc = 4 * c;

    for (int book = 0; book < NB; ++book) {
        const float* bk = books + (size_t)book * (NE * DIM);
        float bval[4] = {-1e30f, -1e30f, -1e30f, -1e30f};
        int bcode[4] = {0, 0, 0, 0};

        for (int ch = 0; ch < NCH; ++ch) {
            __syncthreads();  // cbuf readers done (and resid staged/updated)
            {   // stage chunk: 32 x 1024B wave-instrs, 8 per wave; linear LDS dest,
                // inverse-swizzled global source (same XOR involution as the reads)
                const float* src0 = bk + (size_t)ch * (CCH * DIM);
#pragma unroll
                for (int s = 0; s < 8; ++s) {
                    int inst = wv * 8 + s;            // wave-uniform
                    int row = inst * 2 + (ln >> 5);   // per-lane (source only)
                    int g = ln & 31;
                    int gs = g ^ ((row >> 2) & 7);
                    gload_lds16(src0 + (size_t)row * DIM + gs * 4,
                                (char*)&cbuf[0][0] + inst * 1024);
                }
            }
            __syncthreads();  // compiler drains vmcnt(0) before s_barrier

            float acc[4][4] = {};
#pragma unroll 4
            for (int k4 = 0; k4 < DIM / 4; ++k4) {
                const int oA = (k4 ^ swA) << 2;
                const int oB = (k4 ^ swB) << 2;
                const float4 a0 = *(const float4*)&resid[tr + 0][oA];
                const float4 a1 = *(const float4*)&resid[tr + 1][oA];
                const float4 a2 = *(const float4*)&resid[tr + 2][oA];
                const float4 a3 = *(const float4*)&resid[tr + 3][oA];
                const float4 b0 = *(const float4*)&cbuf[tc + 0][oB];
                const float4 b1 = *(const float4*)&cbuf[tc + 1][oB];
                const float4 b2 = *(const float4*)&cbuf[tc + 2][oB];
                const float4 b3 = *(const float4*)&cbuf[tc + 3][oB];
#define DOT4(J, I, A, B)                                                  \
                acc[J][I] += A.x * B.x; acc[J][I] += A.y * B.y;           \
                acc[J][I] += A.z * B.z; acc[J][I] += A.w * B.w;
                DOT4(0, 0, a0, b0) DOT4(0, 1, a0, b1) DOT4(0, 2, a0, b2) DOT4(0, 3, a0, b3)
                DOT4(1, 0, a1, b0) DOT4(1, 1, a1, b1) DOT4(1, 2, a1, b2) DOT4(1, 3, a1, b3)
                DOT4(2, 0, a2, b0) DOT4(2, 1, a2, b1) DOT4(2, 2, a2, b2) DOT4(2, 3, a2, b3)
                DOT4(3, 0, a3, b0) DOT4(3, 1, a3, b1) DOT4(3, 2, a3, b2) DOT4(3, 3, a3, b3)
#undef DOT4
            }

            const float* hn = hnorm + book * NE + ch * CCH + tc;
#pragma unroll
            for (int i = 0; i < 4; ++i) {
                float h = hn[i];
                int code = ch * CCH + tc + i;  // ascending scan; strict '>' keeps first max
#pragma unroll
                for (int j = 0; j < 4; ++j) {
                    float s = acc[j][i] - h;
                    if (s > bval[j]) { bval[j] = s; bcode[j] = code; }
                }
            }
        }

        // reduce (bval,bcode) across the 16 code-group lanes (xor 1,2,4,8)
#pragma unroll
        for (int j = 0; j < 4; ++j) {
            float v = bval[j];
            int ix = bcode[j];
#pragma unroll
            for (int off = 1; off < 16; off <<= 1) {
                float ov = __shfl_xor(v, off);
                int oi = __shfl_xor(ix, off);
                if (ov > v || (ov == v && oi < ix)) { v = ov; ix = oi; }
            }
            if (c == 0) bidx[tr + j] = ix;
        }
        __syncthreads();  // bidx visible AND all FMA reads of resid done

        // residual -= gathered code (float4; global read coalesced within code row)
        for (int i = tid; i < TPB * (DIM / 4); i += THREADS) {
            int t = i >> 5, g = i & 31;
            float4 q = *(const float4*)&bk[(size_t)bidx[t] * DIM + 4 * g];
            float4* p = (float4*)&resid[t][(g ^ ((t >> 2) & 7)) << 2];
            float4 v = *p;
            v.x -= q.x; v.y -= q.y; v.z -= q.z; v.w -= q.w;
            *p = v;
        }
        // next iteration's first __syncthreads() orders these writes before compute
    }
    __syncthreads();

    // out = x - residual_final (== sum of selected codes)
    for (int i = tid; i < TPB * DIM; i += THREADS) {
        int d = i >> 6, t = i & 63;  // lanes along t -> coalesced global write
        size_t off = zbase + (size_t)d * 2048 + t;
        int g = d >> 2, e = d & 3;
        out[off] = z[off] - resid[t][(((g ^ ((t >> 2) & 7)) << 2) | e)];
    }
}

extern "C" void kernel_launch(void* const* d_in, const int* in_sizes, int n_in,
                              void* d_out, int out_size, void* d_ws, size_t ws_size,
                              hipStream_t stream) {
    const float* z = (const float*)d_in[0];      // [32,128,2048] f32
    const float* books = (const float*)d_in[1];  // [4,1024,128]  f32
    float* out = (float*)d_out;                  // [32,128,2048] f32
    float* hn = (float*)d_ws;                    // 4096 floats scratch

    rvq_norms<<<NB * NE, 64, 0, stream>>>(books, hn);
    rvq_main<<<NTOK / TPB, THREADS, 0, stream>>>(z, books, hn, out);
}

// Round 3
// 312.365 us; speedup vs baseline: 73.4817x; 3.4769x over previous
//
#include <hip/hip_runtime.h>
#include <hip/hip_bf16.h>

#define NB 4
#define NE 1024
#define DIM 128
#define BM 128
#define THREADS 512
#define NBLK 512   // 65536 tokens / 128

typedef __attribute__((ext_vector_type(8))) short bf16x8;
typedef __attribute__((ext_vector_type(4))) float f32x4;

// LDS partition (dynamic, 102912 B total)
#define SMEM_B    65536      // A planes: [32][128] 16B granules = 64 KB
#define SMEM_CAND 98304      // B: 2 x 16 KB double buffer
#define SMEM_BIDX 102400     // cand: int2[4][128] = 4 KB
#define SMEM_TOTAL 102912    // bidx: int[128]

__device__ __forceinline__ unsigned short f2bf(float v) {
    __hip_bfloat16 h = __float2bfloat16(v);
    return __builtin_bit_cast(unsigned short, h);
}
__device__ __forceinline__ float bf2f(unsigned short u) {
    __hip_bfloat16 h = __builtin_bit_cast(__hip_bfloat16, u);
    return __bfloat162float(h);
}
__device__ __forceinline__ void gload_lds16(const void* g, void* l) {
    __builtin_amdgcn_global_load_lds(
        (const __attribute__((address_space(1))) void*)g,
        (__attribute__((address_space(3))) void*)l, 16, 0, 0);
}

// ---- pre-kernel: bake B images (bf16 hi/lo, swizzled LDS layout) + 0.5*||e||^2
// bpre image index = (book*4 + nc)*8 + img ; img 0..3 = eh(dim-group), 4..7 = el
// granule G = (imageIdx*4 + ksub)*256 + (cic ^ (ksub<<1)); each 16 B = 8 bf16
__global__ __launch_bounds__(64) void rvq_pre(const float* __restrict__ books,
                                              char* __restrict__ bpre,
                                              float* __restrict__ hn) {
    const int bc = blockIdx.x;            // book*1024 + code
    const int book = bc >> 10, code = bc & 1023;
    const int j = threadIdx.x;
    const float* e = books + (size_t)bc * DIM;
    if (j < 32) {
        const int jj = j & 15;
        const int d0 = 8 * jj;            // dims d0..d0+7
        float v[8];
#pragma unroll
        for (int m = 0; m < 8; ++m) v[m] = e[d0 + m];
        uint u[4];
        if (j < 16) {                     // hi image
#pragma unroll
            for (int m = 0; m < 4; ++m)
                u[m] = (uint)f2bf(v[2*m]) | ((uint)f2bf(v[2*m+1]) << 16);
        } else {                          // lo image: el = bf16(e - f32(eh))
#pragma unroll
            for (int m = 0; m < 4; ++m) {
                float l0 = v[2*m]   - bf2f(f2bf(v[2*m]));
                float l1 = v[2*m+1] - bf2f(f2bf(v[2*m+1]));
                u[m] = (uint)f2bf(l0) | ((uint)f2bf(l1) << 16);
            }
        }
        const int img  = (j < 16) ? (jj >> 2) : (4 + (jj >> 2));
        const int ksub = jj & 3;
        const int nc = code >> 8, cic = code & 255;
        const int G = ((((book*4 + nc)*8 + img)*4 + ksub) << 8) + (cic ^ (ksub << 1));
        *(uint4*)(bpre + (size_t)G * 16) = make_uint4(u[0], u[1], u[2], u[3]);
        if (j < 16) {                     // norms
            float s = 0.f;
#pragma unroll
            for (int m = 0; m < 8; ++m) s += v[m] * v[m];
#pragma unroll
            for (int off = 1; off < 16; off <<= 1) s += __shfl_xor(s, off);
            if (jj == 0) hn[bc] = 0.5f * s;
        }
    }
}

// stage one 16 KB B-image (step = (book*4+nc)*8+img) into buf (img&1)
__device__ __forceinline__ void stage_step(const char* bpre, char* smem,
                                           int step, int par, int wid, int lane) {
    const char* src = bpre + (size_t)step * 16384;
    char* dst = smem + SMEM_B + par * 16384;
#pragma unroll
    for (int q = 0; q < 2; ++q) {
        int inst = wid * 2 + q;                 // wave-uniform
        gload_lds16(src + inst * 1024 + lane * 16, dst + inst * 1024);
    }
}

// write token's residual slice as bf16 hi/lo into A planes (swizzled)
// planes: hi = seg*4+g (g=dim-granule 0..3), lo = 16 + seg*4+g; row swz: tok^(g<<1)
__device__ __forceinline__ void write_A(char* smem, const float* r, int tok, int seg) {
#pragma unroll
    for (int g = 0; g < 4; ++g) {
        uint uh[4], ul[4];
#pragma unroll
        for (int m = 0; m < 4; ++m) {
            float v0 = r[8*g + 2*m], v1 = r[8*g + 2*m + 1];
            unsigned short h0 = f2bf(v0), h1 = f2bf(v1);
            float l0 = v0 - bf2f(h0), l1 = v1 - bf2f(h1);
            uh[m] = (uint)h0 | ((uint)h1 << 16);
            ul[m] = (uint)f2bf(l0) | ((uint)f2bf(l1) << 16);
        }
        const int rw = tok ^ (g << 1);
        *(uint4*)(smem + (((seg*4 + g)      << 7) + rw) * 16) = make_uint4(uh[0], uh[1], uh[2], uh[3]);
        *(uint4*)(smem + (((16 + seg*4 + g) << 7) + rw) * 16) = make_uint4(ul[0], ul[1], ul[2], ul[3]);
    }
}

__global__ __launch_bounds__(THREADS, 1) void rvq_mfma(
        const float* __restrict__ z, const float* __restrict__ books,
        const char* __restrict__ bpre, const float* __restrict__ hn,
        float* __restrict__ out) {
    extern __shared__ char smem[];
    const int tid = threadIdx.x;
    const int wid = tid >> 6, lane = tid & 63;
    const int lr = lane & 15, lh = lane >> 4;   // C: col=lr, row base=lh*4
    const int mw = wid >> 2, nw = wid & 3;      // wave grid 2M x 4N
    const int tok = tid & 127, seg = tid >> 7;  // update ownership: token, dim-seg

    const int t0 = blockIdx.x * BM;
    const int bb = t0 >> 11, tin = t0 & 2047;
    const size_t zbase = (size_t)bb * (DIM * 2048) + tin;

    float resid[32];                            // fp32 residual, dims 32*seg..+31
#pragma unroll
    for (int j = 0; j < 32; ++j)
        resid[j] = z[zbase + (size_t)(32*seg + j) * 2048 + tok];
    write_A(smem, resid, tok, seg);
    stage_step(bpre, smem, 0, 0, wid, lane);

    for (int book = 0; book < NB; ++book) {
        float bval[4][4];
        int bcode[4][4];
#pragma unroll
        for (int a = 0; a < 4; ++a)
#pragma unroll
            for (int b = 0; b < 4; ++b) { bval[a][b] = -1e30f; bcode[a][b] = 0; }

        for (int nc = 0; nc < 4; ++nc) {
            float hnv[4];
#pragma unroll
            for (int nt = 0; nt < 4; ++nt)
                hnv[nt] = hn[book*NE + nc*256 + nw*64 + nt*16 + lr];
            f32x4 acc[4][4];
#pragma unroll
            for (int a = 0; a < 4; ++a)
#pragma unroll
                for (int b = 0; b < 4; ++b) acc[a][b] = (f32x4){0.f, 0.f, 0.f, 0.f};

#pragma unroll
            for (int img = 0; img < 8; ++img) {
                __syncthreads();               // stage done (vmcnt drain) + A ready
                const bool last = (nc == 3) && (img == 7);
                if (!last)
                    stage_step(bpre, smem, book*32 + nc*8 + img + 1, (img & 1) ^ 1, wid, lane);
                const int dg = img & 3;
                const char* Bb = smem + SMEM_B + (img & 1) * 16384;
                bf16x8 ah[4], al[4], bv[4];
#pragma unroll
                for (int nt = 0; nt < 4; ++nt) {
                    int code = nw*64 + nt*16 + lr;
                    bv[nt] = *(const bf16x8*)(Bb + (((lh << 8) + (code ^ (lh << 1))) * 16));
                }
#pragma unroll
                for (int mt = 0; mt < 4; ++mt) {
                    int rsw = (mw*64 + mt*16 + lr) ^ (lh << 1);
                    ah[mt] = *(const bf16x8*)(smem + ((((dg*4 + lh)      << 7) + rsw) * 16));
                    al[mt] = *(const bf16x8*)(smem + ((((16 + dg*4 + lh) << 7) + rsw) * 16));
                }
#pragma unroll
                for (int mt = 0; mt < 4; ++mt)
#pragma unroll
                    for (int nt = 0; nt < 4; ++nt)
                        acc[mt][nt] = __builtin_amdgcn_mfma_f32_16x16x32_bf16(ah[mt], bv[nt], acc[mt][nt], 0, 0, 0);
#pragma unroll
                for (int mt = 0; mt < 4; ++mt)
#pragma unroll
                    for (int nt = 0; nt < 4; ++nt)
                        acc[mt][nt] = __builtin_amdgcn_mfma_f32_16x16x32_bf16(al[mt], bv[nt], acc[mt][nt], 0, 0, 0);
            }
            // fold chunk scores into running argmax (codes ascend -> strict '>')
#pragma unroll
            for (int mt = 0; mt < 4; ++mt)
#pragma unroll
                for (int nt = 0; nt < 4; ++nt) {
                    int code = nc*256 + nw*64 + nt*16 + lr;
#pragma unroll
                    for (int rg = 0; rg < 4; ++rg) {
                        float sc = acc[mt][nt][rg] - hnv[nt];
                        if (sc > bval[mt][rg]) { bval[mt][rg] = sc; bcode[mt][rg] = code; }
                    }
                }
        }
        // reduce across the 16 code-columns (lanes xor 1,2,4,8)
#pragma unroll
        for (int mt = 0; mt < 4; ++mt)
#pragma unroll
            for (int rg = 0; rg < 4; ++rg) {
                float v = bval[mt][rg]; int ix = bcode[mt][rg];
#pragma unroll
                for (int off = 1; off < 16; off <<= 1) {
                    float ov = __shfl_xor(v, off);
                    int oi = __shfl_xor(ix, off);
                    if (ov > v || (ov == v && oi < ix)) { v = ov; ix = oi; }
                }
                if (lr == 0) {
                    int token = mw*64 + mt*16 + lh*4 + rg;
                    ((int2*)(smem + SMEM_CAND))[nw*128 + token] =
                        make_int2(__float_as_int(v), ix);
                }
            }
        __syncthreads();
        if (tid < BM) {   // combine the 4 N-wave candidates (nw ascending = code ascending)
            const int2* cp = (const int2*)(smem + SMEM_CAND);
            float bw = -1e30f; int bi = 0;
#pragma unroll
            for (int w = 0; w < 4; ++w) {
                int2 cd = cp[w*128 + tid];
                float v = __int_as_float(cd.x);
                if (v > bw || (v == bw && cd.y < bi)) { bw = v; bi = cd.y; }
            }
            ((int*)(smem + SMEM_BIDX))[tid] = bi;
        }
        __syncthreads();
        const int bi = ((const int*)(smem + SMEM_BIDX))[tok];
        const float* eb = books + ((size_t)(book*NE + bi) * DIM + 32*seg);
#pragma unroll
        for (int g = 0; g < 8; ++g) {
            float4 q = *(const float4*)(eb + 4*g);
            resid[4*g+0] -= q.x; resid[4*g+1] -= q.y;
            resid[4*g+2] -= q.z; resid[4*g+3] -= q.w;
        }
        if (book < NB - 1) {
            write_A(smem, resid, tok, seg);     // A-reads all retired 2 barriers ago
            stage_step(bpre, smem, (book + 1) * 32, 0, wid, lane);
        }
    }
    // out = z - resid_final  (== sum of selected codes)
#pragma unroll
    for (int j = 0; j < 32; ++j) {
        size_t off = zbase + (size_t)(32*seg + j) * 2048 + tok;
        out[off] = z[off] - resid[j];
    }
}

extern "C" void kernel_launch(void* const* d_in, const int* in_sizes, int n_in,
                              void* d_out, int out_size, void* d_ws, size_t ws_size,
                              hipStream_t stream) {
    const float* z = (const float*)d_in[0];      // [32,128,2048] f32
    const float* books = (const float*)d_in[1];  // [4,1024,128]  f32
    float* out = (float*)d_out;                  // [32,128,2048] f32
    char* bpre = (char*)d_ws;                    // 2 MB B-images
    float* hnp = (float*)((char*)d_ws + 2097152);// 16 KB norms

    hipFuncSetAttribute((const void*)rvq_mfma,
                        hipFuncAttributeMaxDynamicSharedMemorySize, SMEM_TOTAL);
    rvq_pre<<<NB * NE, 64, 0, stream>>>(books, bpre, hnp);
    rvq_mfma<<<NBLK, THREADS, SMEM_TOTAL, stream>>>(z, books, bpre, hnp, out);
}